// Round 2
// baseline (539.221 us; speedup 1.0000x reference)
//
#include <hip/hip_runtime.h>

typedef __attribute__((ext_vector_type(8))) short s8v;   // 8 bf16
typedef __attribute__((ext_vector_type(4))) short s4v;   // 4 bf16
typedef __attribute__((ext_vector_type(4))) float f4v;   // MFMA C/D

#define S_ 4096
#define E_ 1024
#define D_ 128

#if defined(__has_builtin)
#if __has_builtin(__builtin_amdgcn_mfma_f32_16x16x16bf16_1k)
#define HAVE_MFMA16 1
#endif
#endif
#ifndef HAVE_MFMA16
#define HAVE_MFMA16 0
#endif

__device__ __forceinline__ unsigned short f2bf(float f) {
  unsigned int u = __float_as_uint(f);
  return (unsigned short)((u + 0x7FFFu + ((u >> 16) & 1u)) >> 16);
}

// ---- W cvt+transpose: W[p][k][n] f32 -> Wt[p*128+n][k] bf16 ----------------
__global__ __launch_bounds__(256) void wcvt_kernel(
    const float* __restrict__ Wq, const float* __restrict__ Wk,
    const float* __restrict__ Wv, unsigned short* __restrict__ Wt) {
  __shared__ unsigned short T[64][72];
  const int p = blockIdx.y;
  const float* W = (p == 0) ? Wq : (p == 1) ? Wk : Wv;
  const int k0 = (blockIdx.x >> 1) * 64;
  const int n0 = (blockIdx.x & 1) * 64;
  const int t = threadIdx.x, rr = t >> 4, c4 = (t & 15) * 4;
#pragma unroll
  for (int i = 0; i < 4; ++i) {
    int kr = i * 16 + rr;
    float4 w = *reinterpret_cast<const float4*>(W + (size_t)(k0 + kr) * D_ + n0 + c4);
    T[c4 + 0][kr] = f2bf(w.x); T[c4 + 1][kr] = f2bf(w.y);
    T[c4 + 2][kr] = f2bf(w.z); T[c4 + 3][kr] = f2bf(w.w);
  }
  __syncthreads();
#pragma unroll
  for (int i = 0; i < 4; ++i) {
    int n = i * 16 + rr;
    s4v v;
    v[0] = (short)T[n][c4]; v[1] = (short)T[n][c4 + 1];
    v[2] = (short)T[n][c4 + 2]; v[3] = (short)T[n][c4 + 3];
    *reinterpret_cast<s4v*>(Wt + (size_t)(p * D_ + n0 + n) * E_ + k0 + c4) = v;
  }
}

// ---- fused QKV projection: barrier-free, LDS-free ---------------------------
// grid (128, 2): block = 128 rows; wave = 32 rows x 12 n-tiles (of 24 total).
__global__ __launch_bounds__(256) void proj_kernel(
    const float* __restrict__ x, const unsigned short* __restrict__ Wt,
    unsigned short* __restrict__ Qb, unsigned short* __restrict__ Kb,
    unsigned short* __restrict__ Vb) {
  const int t = threadIdx.x;
  const int wv = t >> 6, lane = t & 63, quad = lane >> 4, l16 = lane & 15;
  const int mb = blockIdx.x * 128 + wv * 32;
  const int nb = blockIdx.y * 12;

  f4v acc[24];
  const f4v fz = {0.f, 0.f, 0.f, 0.f};
#pragma unroll
  for (int i = 0; i < 24; ++i) acc[i] = fz;

  const float* xp0 = x + (size_t)(mb + l16) * E_ + quad * 8;
  const float* xp1 = xp0 + (size_t)16 * E_;
  const unsigned short* wp = Wt + (size_t)(nb * 16 + l16) * E_ + quad * 8;

#pragma unroll 2
  for (int kk = 0; kk < E_; kk += 32) {
    float4 a00 = *reinterpret_cast<const float4*>(xp0 + kk);
    float4 a01 = *reinterpret_cast<const float4*>(xp0 + kk + 4);
    float4 a10 = *reinterpret_cast<const float4*>(xp1 + kk);
    float4 a11 = *reinterpret_cast<const float4*>(xp1 + kk + 4);
    s8v af0, af1;
    af0[0] = (short)f2bf(a00.x); af0[1] = (short)f2bf(a00.y);
    af0[2] = (short)f2bf(a00.z); af0[3] = (short)f2bf(a00.w);
    af0[4] = (short)f2bf(a01.x); af0[5] = (short)f2bf(a01.y);
    af0[6] = (short)f2bf(a01.z); af0[7] = (short)f2bf(a01.w);
    af1[0] = (short)f2bf(a10.x); af1[1] = (short)f2bf(a10.y);
    af1[2] = (short)f2bf(a10.z); af1[3] = (short)f2bf(a10.w);
    af1[4] = (short)f2bf(a11.x); af1[5] = (short)f2bf(a11.y);
    af1[6] = (short)f2bf(a11.z); af1[7] = (short)f2bf(a11.w);
#pragma unroll
    for (int ntl = 0; ntl < 12; ++ntl) {
      s8v bf = *reinterpret_cast<const s8v*>(wp + (size_t)ntl * 16 * E_ + kk);
      acc[ntl] = __builtin_amdgcn_mfma_f32_16x16x32_bf16(af0, bf, acc[ntl], 0, 0, 0);
      acc[12 + ntl] = __builtin_amdgcn_mfma_f32_16x16x32_bf16(af1, bf, acc[12 + ntl], 0, 0, 0);
    }
  }
#pragma unroll
  for (int ntl = 0; ntl < 12; ++ntl) {
    int N = (nb + ntl) * 16 + l16;
    unsigned short* dst = (N < 128) ? Qb : (N < 256) ? Kb : Vb;
    int col = N & 127;
#pragma unroll
    for (int sub = 0; sub < 2; ++sub)
#pragma unroll
      for (int r = 0; r < 4; ++r) {
        int row = mb + sub * 16 + quad * 4 + r;
        dst[(size_t)row * D_ + col] = f2bf(acc[sub * 12 + ntl][r]);
      }
  }
}

// ---- V transpose: Vb[16384][128] bf16 -> VT[b][128][4096] bf16 -------------
__global__ __launch_bounds__(256) void vtrans_kernel(
    const unsigned short* __restrict__ Vb, unsigned short* __restrict__ VT) {
  __shared__ unsigned short T[64][72];
  const int s0g = blockIdx.x * 64;
  const int d0 = blockIdx.y * 64;
  const int t = threadIdx.x, rr = t >> 4, c4 = (t & 15) * 4;
#pragma unroll
  for (int i = 0; i < 4; ++i) {
    int sr = i * 16 + rr;
    s4v v = *reinterpret_cast<const s4v*>(Vb + (size_t)(s0g + sr) * D_ + d0 + c4);
    T[c4 + 0][sr] = (unsigned short)v[0]; T[c4 + 1][sr] = (unsigned short)v[1];
    T[c4 + 2][sr] = (unsigned short)v[2]; T[c4 + 3][sr] = (unsigned short)v[3];
  }
  __syncthreads();
  const int b = s0g >> 12, sl = s0g & (S_ - 1);
#pragma unroll
  for (int i = 0; i < 4; ++i) {
    int d = i * 16 + rr;
    s4v v;
    v[0] = (short)T[d][c4]; v[1] = (short)T[d][c4 + 1];
    v[2] = (short)T[d][c4 + 2]; v[3] = (short)T[d][c4 + 3];
    *reinterpret_cast<s4v*>(VT + (size_t)(b * D_ + d0 + d) * S_ + sl + c4) = v;
  }
}

// ---- flash attention: no-max softmax, S^T layout, barrier-free main loop ---
__global__ __launch_bounds__(256) void flash_kernel(
    const unsigned short* __restrict__ Qb, const unsigned short* __restrict__ Kb,
    const unsigned short* __restrict__ VT, float* __restrict__ out) {
  __shared__ float smem[4 * 2048 + 256];  // Ow[4][16][128] | lpart[4][4][16]
  const int qt = blockIdx.x, b = blockIdx.y, q0 = qt * 16;
  const int t = threadIdx.x;
  const int wv = t >> 6, lane = t & 63, quad = lane >> 4, l16 = lane & 15;
  const float SCL2 = 0.03125f * 1.44269504088896340736f;  // scale * log2(e)

  // Q as B-operand fragments (loop-invariant)
  s8v Qf[4];
  const unsigned short* qp = Qb + ((size_t)b * S_ + q0 + l16) * D_ + quad * 8;
#pragma unroll
  for (int ks = 0; ks < 4; ++ks) Qf[ks] = *reinterpret_cast<const s8v*>(qp + ks * 32);

  f4v O[8];
  const f4v fz = {0.f, 0.f, 0.f, 0.f};
#pragma unroll
  for (int i = 0; i < 8; ++i) O[i] = fz;
  f4v lacc = fz;  // partial row-sums: query=l16, this lane's keys

  const unsigned short* Kbb = Kb + (size_t)b * S_ * D_;
  const unsigned short* Vbb = VT + (size_t)b * D_ * S_;

  const int nkb = (q0 + 47) >> 5;
  for (int kb = wv; kb < nkb; kb += 4) {
    const int k0 = kb * 32;
#pragma unroll
    for (int kt = 0; kt < 2; ++kt) {
      const int kbase = k0 + kt * 16;
#if HAVE_MFMA16
      if (kbase > q0 + 15) continue;  // fully-masked subtile (wave-uniform)
#endif
      // S^T = K . Q^T  (key rows = A, so C-layout key=quad*4+r, query=l16)
      f4v St = fz;
#pragma unroll
      for (int ks = 0; ks < 4; ++ks) {
        s8v kf = *reinterpret_cast<const s8v*>(
            Kbb + (size_t)(kbase + l16) * D_ + ks * 32 + quad * 8);
        St = __builtin_amdgcn_mfma_f32_16x16x32_bf16(kf, Qf[ks], St, 0, 0, 0);
      }
      float pv[4];
      const bool msk = (kbase + 15 > q0);
      if (msk) {
#pragma unroll
        for (int r = 0; r < 4; ++r) {
          int key = kbase + quad * 4 + r;
          pv[r] = (key <= q0 + l16) ? exp2f(St[r] * SCL2) : 0.f;
        }
      } else {
#pragma unroll
        for (int r = 0; r < 4; ++r) pv[r] = exp2f(St[r] * SCL2);
      }
#pragma unroll
      for (int r = 0; r < 4; ++r) lacc[r] += pv[r];
#if HAVE_MFMA16
      // P^T C-layout == A-layout of K=16 MFMA: feed directly, no data movement
      s4v pf;
#pragma unroll
      for (int r = 0; r < 4; ++r) pf[r] = (short)f2bf(pv[r]);
#pragma unroll
      for (int nt = 0; nt < 8; ++nt) {
        s4v vf = *reinterpret_cast<const s4v*>(
            Vbb + (size_t)(nt * 16 + l16) * S_ + kbase + quad * 4);
        O[nt] = __builtin_amdgcn_mfma_f32_16x16x16bf16_1k(pf, vf, O[nt], 0, 0, 0);
      }
#else
      {
        unsigned short* pbuf = reinterpret_cast<unsigned short*>(&smem[wv * 2048]);
#pragma unroll
        for (int r = 0; r < 4; ++r)
          pbuf[l16 * 32 + kt * 16 + quad * 4 + r] = f2bf(pv[r]);
      }
#endif
    }
#if !HAVE_MFMA16
    {
      unsigned short* pbuf = reinterpret_cast<unsigned short*>(&smem[wv * 2048]);
      s8v Pf = *reinterpret_cast<const s8v*>(&pbuf[l16 * 32 + quad * 8]);
#pragma unroll
      for (int nt = 0; nt < 8; ++nt) {
        s8v vf = *reinterpret_cast<const s8v*>(
            Vbb + (size_t)(nt * 16 + l16) * S_ + k0 + quad * 8);
        O[nt] = __builtin_amdgcn_mfma_f32_16x16x32_bf16(Pf, vf, O[nt], 0, 0, 0);
      }
    }
#endif
  }

  // per-wave results -> LDS
  float ls = lacc[0] + lacc[1] + lacc[2] + lacc[3];
  float* Ow = &smem[wv * 2048];
#pragma unroll
  for (int nt = 0; nt < 8; ++nt)
#pragma unroll
    for (int r = 0; r < 4; ++r)
      Ow[(quad * 4 + r) * 128 + nt * 16 + l16] = O[nt][r];
  smem[8192 + wv * 64 + quad * 16 + l16] = ls;  // lpart[w][quad][query]
  __syncthreads();

  // combine 4 waves (pure sums — no rescale needed), normalize, store
  const int col = t & 127;
  const int half = t >> 7;
#pragma unroll
  for (int i = 0; i < 8; ++i) {
    int r = half * 8 + i;
    float Os = 0.f, L = 0.f;
#pragma unroll
    for (int w = 0; w < 4; ++w) {
      Os += smem[w * 2048 + r * 128 + col];
      L += smem[8192 + w * 64 + r] + smem[8192 + w * 64 + 16 + r] +
           smem[8192 + w * 64 + 32 + r] + smem[8192 + w * 64 + 48 + r];
    }
    out[((size_t)b * S_ + q0 + r) * D_ + col] = Os / L;
  }
}

extern "C" void kernel_launch(void* const* d_in, const int* in_sizes, int n_in,
                              void* d_out, int out_size, void* d_ws, size_t ws_size,
                              hipStream_t stream) {
  const float* x = (const float*)d_in[0];
  const float* Wq = (const float*)d_in[1];
  const float* Wk = (const float*)d_in[2];
  const float* Wv = (const float*)d_in[3];
  float* out = (float*)d_out;

  unsigned short* Qb = (unsigned short*)d_ws;        // [16384][128]
  unsigned short* Kb = Qb + (size_t)16384 * 128;     // [16384][128]
  unsigned short* Vb = Kb + (size_t)16384 * 128;     // [16384][128]
  unsigned short* VT = Vb + (size_t)16384 * 128;     // [4][128][4096]
  unsigned short* Wt = VT + (size_t)16384 * 128;     // [384][1024]

  wcvt_kernel<<<dim3(32, 3), 256, 0, stream>>>(Wq, Wk, Wv, Wt);
  proj_kernel<<<dim3(128, 2), 256, 0, stream>>>(x, Wt, Qb, Kb, Vb);
  vtrans_kernel<<<dim3(256, 2), 256, 0, stream>>>(Vb, VT);
  flash_kernel<<<dim3(256, 4), 256, 0, stream>>>(Qb, Kb, VT, out);
}

// Round 3
// 288.204 us; speedup vs baseline: 1.8710x; 1.8710x over previous
//
#include <hip/hip_runtime.h>

typedef __attribute__((ext_vector_type(8))) short s8v;   // 8 bf16
typedef __attribute__((ext_vector_type(4))) short s4v;   // 4 bf16
typedef __attribute__((ext_vector_type(4))) float f4v;   // MFMA C/D

#define S_ 4096
#define E_ 1024
#define D_ 128

__device__ __forceinline__ unsigned short f2bf(float f) {
  unsigned int u = __float_as_uint(f);
  return (unsigned short)((u + 0x7FFFu + ((u >> 16) & 1u)) >> 16);
}

// ---- W cvt+transpose: W[p][k][n] f32 -> Wt[p*128+n][k] bf16 ----------------
__global__ __launch_bounds__(256) void wcvt_kernel(
    const float* __restrict__ Wq, const float* __restrict__ Wk,
    const float* __restrict__ Wv, unsigned short* __restrict__ Wt) {
  __shared__ unsigned short T[64][72];
  const int p = blockIdx.y;
  const float* W = (p == 0) ? Wq : (p == 1) ? Wk : Wv;
  const int k0 = (blockIdx.x >> 1) * 64;
  const int n0 = (blockIdx.x & 1) * 64;
  const int t = threadIdx.x, rr = t >> 4, c4 = (t & 15) * 4;
#pragma unroll
  for (int i = 0; i < 4; ++i) {
    int kr = i * 16 + rr;
    float4 w = *reinterpret_cast<const float4*>(W + (size_t)(k0 + kr) * D_ + n0 + c4);
    T[c4 + 0][kr] = f2bf(w.x); T[c4 + 1][kr] = f2bf(w.y);
    T[c4 + 2][kr] = f2bf(w.z); T[c4 + 3][kr] = f2bf(w.w);
  }
  __syncthreads();
#pragma unroll
  for (int i = 0; i < 4; ++i) {
    int n = i * 16 + rr;
    s4v v;
    v[0] = (short)T[n][c4]; v[1] = (short)T[n][c4 + 1];
    v[2] = (short)T[n][c4 + 2]; v[3] = (short)T[n][c4 + 3];
    *reinterpret_cast<s4v*>(Wt + (size_t)(p * D_ + n0 + n) * E_ + k0 + c4) = v;
  }
}

// ---- fused QKV projection ---------------------------------------------------
// grid 256: block = 64 rows (4 waves x 16 rows), each wave all 384 out cols.
// x read once from HBM (64MB, ~10us floor); Wt L1-shared across waves.
// Writes Q,K row-major bf16 and V directly transposed (VT[b][d][s]).
__global__ __launch_bounds__(256) void proj_kernel(
    const float* __restrict__ x, const unsigned short* __restrict__ Wt,
    unsigned short* __restrict__ Qb, unsigned short* __restrict__ Kb,
    unsigned short* __restrict__ VT) {
  const int t = threadIdx.x;
  const int wv = t >> 6, lane = t & 63, quad = lane >> 4, l16 = lane & 15;
  const int m0 = blockIdx.x * 64 + wv * 16;

  f4v acc[24];
  const f4v fz = {0.f, 0.f, 0.f, 0.f};
#pragma unroll
  for (int i = 0; i < 24; ++i) acc[i] = fz;

  const float* xp = x + (size_t)(m0 + l16) * E_ + quad * 8;
  const unsigned short* wp = Wt + (size_t)l16 * E_ + quad * 8;

  float4 a0 = *reinterpret_cast<const float4*>(xp);
  float4 a1 = *reinterpret_cast<const float4*>(xp + 4);
  for (int kk = 0; kk < E_; kk += 32) {
    float4 n0 = a0, n1 = a1;
    if (kk + 32 < E_) {  // register double-buffer: next x chunk in flight
      n0 = *reinterpret_cast<const float4*>(xp + kk + 32);
      n1 = *reinterpret_cast<const float4*>(xp + kk + 36);
    }
    s8v af;
    af[0] = (short)f2bf(a0.x); af[1] = (short)f2bf(a0.y);
    af[2] = (short)f2bf(a0.z); af[3] = (short)f2bf(a0.w);
    af[4] = (short)f2bf(a1.x); af[5] = (short)f2bf(a1.y);
    af[6] = (short)f2bf(a1.z); af[7] = (short)f2bf(a1.w);
#pragma unroll
    for (int ntl = 0; ntl < 24; ++ntl) {
      s8v bf = *reinterpret_cast<const s8v*>(wp + (size_t)ntl * 16 * E_ + kk);
      acc[ntl] = __builtin_amdgcn_mfma_f32_16x16x32_bf16(af, bf, acc[ntl], 0, 0, 0);
    }
    a0 = n0; a1 = n1;
  }

  const int b = m0 >> 12, sbase = (m0 & (S_ - 1)) + quad * 4;
#pragma unroll
  for (int ntl = 0; ntl < 24; ++ntl) {
    int N = ntl * 16 + l16;
    if (N < 256) {  // Q or K: row-major bf16
      unsigned short* dst = (N < 128) ? Qb : Kb;
      int col = N & 127;
#pragma unroll
      for (int r = 0; r < 4; ++r)
        dst[(size_t)(m0 + quad * 4 + r) * D_ + col] = f2bf(acc[ntl][r]);
    } else {  // V: transposed write VT[b][d][s], 4 consecutive s -> 8B store
      int d = N - 256;
      s4v v;
      v[0] = (short)f2bf(acc[ntl][0]); v[1] = (short)f2bf(acc[ntl][1]);
      v[2] = (short)f2bf(acc[ntl][2]); v[3] = (short)f2bf(acc[ntl][3]);
      *reinterpret_cast<s4v*>(VT + ((size_t)b * D_ + d) * S_ + sbase) = v;
    }
  }
}

// ---- flash attention: causal, no-max softmax, barrier-free main loop -------
// 512 blocks: id%8 -> (batch, half) pins each batch to one XCD pair (L2
// locality); heavy q-tiles first. Block = 32 q-rows; 4 waves split keys.
// S^T trick with permuted key rows so P exits QK directly in the K=32
// A-fragment layout for PV (no LDS / shuffles in the loop).
__global__ __launch_bounds__(256, 2) void flash_kernel(
    const unsigned short* __restrict__ Qb, const unsigned short* __restrict__ Kb,
    const unsigned short* __restrict__ VT, float* __restrict__ out) {
  __shared__ float Ow[4][32][128];
  __shared__ float lw[4][32];
  const int id = blockIdx.x;
  const int r8 = id & 7, g = id >> 3;
  const int b = r8 >> 1;
  const int qt = 127 - (g * 2 + (r8 & 1));  // heavy-first
  const int q0 = qt * 32;
  const int t = threadIdx.x;
  const int wv = t >> 6, lane = t & 63, quad = lane >> 4, l16 = lane & 15;
  const float SCL2 = 0.03125f * 1.44269504088896340736f;  // (1/32)*log2(e)

  const unsigned short* Kbb = Kb + (size_t)b * S_ * D_;
  const unsigned short* Vbb = VT + (size_t)b * D_ * S_;

  s8v Qf[2][4];  // B-operand: n=l16 -> q row, k=quad*8+j -> d
#pragma unroll
  for (int t2 = 0; t2 < 2; ++t2)
#pragma unroll
    for (int ks = 0; ks < 4; ++ks)
      Qf[t2][ks] = *reinterpret_cast<const s8v*>(
          Qb + ((size_t)b * S_ + q0 + t2 * 16 + l16) * D_ + ks * 32 + quad * 8);

  f4v O[2][8];
  const f4v fz = {0.f, 0.f, 0.f, 0.f};
#pragma unroll
  for (int t2 = 0; t2 < 2; ++t2)
#pragma unroll
    for (int nt = 0; nt < 8; ++nt) O[t2][nt] = fz;
  float lt[2] = {0.f, 0.f};

  const int nkb = qt + 1;
  const int keyrow = ((l16 >> 2) << 3) + (l16 & 3);  // permuted A-row -> key

  for (int kb = wv; kb < nkb; kb += 4) {
    const int k0 = kb * 32;
    // V fragments first (consumed last -> max latency overlap)
    s8v vfr[8];
#pragma unroll
    for (int nt = 0; nt < 8; ++nt)
      vfr[nt] = *reinterpret_cast<const s8v*>(
          Vbb + (size_t)(nt * 16 + l16) * S_ + k0 + quad * 8);
    s8v kf[2][4];
#pragma unroll
    for (int s2 = 0; s2 < 2; ++s2)
#pragma unroll
      for (int ks = 0; ks < 4; ++ks)
        kf[s2][ks] = *reinterpret_cast<const s8v*>(
            Kbb + (size_t)(k0 + keyrow + s2 * 4) * D_ + ks * 32 + quad * 8);
    f4v St[2][2];  // [s][t]
    St[0][0] = fz; St[0][1] = fz; St[1][0] = fz; St[1][1] = fz;
#pragma unroll
    for (int ks = 0; ks < 4; ++ks)
#pragma unroll
      for (int s2 = 0; s2 < 2; ++s2)
#pragma unroll
        for (int t2 = 0; t2 < 2; ++t2)
          St[s2][t2] = __builtin_amdgcn_mfma_f32_16x16x32_bf16(
              kf[s2][ks], Qf[t2][ks], St[s2][t2], 0, 0, 0);

    const bool full = (k0 + 31 <= q0);  // wave-uniform
    s8v pf[2];
#pragma unroll
    for (int t2 = 0; t2 < 2; ++t2) {
      float ladd = 0.f;
#pragma unroll
      for (int s2 = 0; s2 < 2; ++s2)
#pragma unroll
        for (int r = 0; r < 4; ++r) {
          float e = exp2f(St[s2][t2][r] * SCL2);
          if (!full) {
            int key = k0 + quad * 8 + s2 * 4 + r;
            int q = q0 + t2 * 16 + l16;
            if (key > q) e = 0.f;
          }
          ladd += e;
          pf[t2][s2 * 4 + r] = (short)f2bf(e);
        }
      lt[t2] += ladd;
    }
    // O += P V  (P already in K=32 A-layout thanks to key permutation)
#pragma unroll
    for (int nt = 0; nt < 8; ++nt)
#pragma unroll
      for (int t2 = 0; t2 < 2; ++t2)
        O[t2][nt] = __builtin_amdgcn_mfma_f32_16x16x32_bf16(
            pf[t2], vfr[nt], O[t2][nt], 0, 0, 0);
  }

  // epilogue: combine 4 key-split waves (pure sums, no-max softmax)
#pragma unroll
  for (int t2 = 0; t2 < 2; ++t2) {
    float v = lt[t2];
    v += __shfl_xor(v, 16);
    v += __shfl_xor(v, 32);
    lt[t2] = v;
  }
  if (lane < 16) { lw[wv][l16] = lt[0]; lw[wv][16 + l16] = lt[1]; }
#pragma unroll
  for (int t2 = 0; t2 < 2; ++t2)
#pragma unroll
    for (int nt = 0; nt < 8; ++nt)
#pragma unroll
      for (int r = 0; r < 4; ++r)
        Ow[wv][t2 * 16 + quad * 4 + r][nt * 16 + l16] = O[t2][nt][r];
  __syncthreads();

  const int col = t & 127, rbase = (t >> 7) * 16;
#pragma unroll
  for (int i = 0; i < 16; ++i) {
    int row = rbase + i;
    float L = lw[0][row] + lw[1][row] + lw[2][row] + lw[3][row];
    float Os = Ow[0][row][col] + Ow[1][row][col] + Ow[2][row][col] + Ow[3][row][col];
    out[((size_t)b * S_ + q0 + row) * D_ + col] = Os / L;
  }
}

extern "C" void kernel_launch(void* const* d_in, const int* in_sizes, int n_in,
                              void* d_out, int out_size, void* d_ws, size_t ws_size,
                              hipStream_t stream) {
  const float* x = (const float*)d_in[0];
  const float* Wq = (const float*)d_in[1];
  const float* Wk = (const float*)d_in[2];
  const float* Wv = (const float*)d_in[3];
  float* out = (float*)d_out;

  unsigned short* Qb = (unsigned short*)d_ws;        // [16384][128]
  unsigned short* Kb = Qb + (size_t)16384 * 128;     // [16384][128]
  unsigned short* VT = Kb + (size_t)16384 * 128;     // [4][128][4096]
  unsigned short* Wt = VT + (size_t)16384 * 128;     // [384][1024]

  wcvt_kernel<<<dim3(32, 3), 256, 0, stream>>>(Wq, Wk, Wv, Wt);
  proj_kernel<<<256, 256, 0, stream>>>(x, Wt, Qb, Kb, VT);
  flash_kernel<<<512, 256, 0, stream>>>(Qb, Kb, VT, out);
}